// Round 9
// baseline (213.800 us; speedup 1.0000x reference)
//
#include <hip/hip_runtime.h>

typedef unsigned short u16;
typedef short s16x8 __attribute__((ext_vector_type(8)));
typedef u16 u16x8 __attribute__((ext_vector_type(8)));
typedef u16 u16x4 __attribute__((ext_vector_type(4)));
typedef float f32x4 __attribute__((ext_vector_type(4)));
typedef _Float16 h16x8 __attribute__((ext_vector_type(8)));
typedef __fp16 fp16x2 __attribute__((ext_vector_type(2)));

// ---- helpers -------------------------------------------------------------

__device__ inline u16 f2bf(float f) {
  union { float f; unsigned u; } x; x.f = f;
  unsigned r = x.u + 0x7fffu + ((x.u >> 16) & 1u);   // RNE
  return (u16)(r >> 16);
}

__device__ inline u16 f2h(float f) {
  _Float16 h = (_Float16)f;
  union { _Float16 h; u16 u; } x; x.h = h;
  return x.u;
}

__device__ inline void gld16(const u16* g, u16* l) {
  __builtin_amdgcn_global_load_lds(
      (const __attribute__((address_space(1))) void*)g,
      (__attribute__((address_space(3))) void*)l, 16, 0, 0);
}

// ---- 1. fused prep: fp32->bf16 convert of q,k,v + weight transposes ------
__global__ __launch_bounds__(256) void k_prep(const float* __restrict__ q,
                                              const float* __restrict__ k,
                                              const float* __restrict__ v,
                                              const float* __restrict__ Wq,
                                              const float* __restrict__ Wk,
                                              const float* __restrict__ Wv,
                                              const float* __restrict__ Wo,
                                              u16* __restrict__ dst,
                                              u16* __restrict__ WT,
                                              u16* __restrict__ WOT) {
  __shared__ float tile[64][65];
  const int bid = blockIdx.x;
  if (bid < 6144) {
    const int m = bid >> 11;
    const int xi = bid & 2047;
    const float* src = (m == 0) ? q : (m == 1) ? k : v;
    u16* d = dst + (size_t)m * (4096u * 1024u);
    size_t i0 = ((size_t)xi * 256 + threadIdx.x) * 8;
    float4 a = *(const float4*)(src + i0);
    float4 b = *(const float4*)(src + i0 + 4);
    u16x8 o;
    o[0] = f2bf(a.x); o[1] = f2bf(a.y); o[2] = f2bf(a.z); o[3] = f2bf(a.w);
    o[4] = f2bf(b.x); o[5] = f2bf(b.y); o[6] = f2bf(b.z); o[7] = f2bf(b.w);
    *(u16x8*)(d + i0) = o;
    return;
  }
  const int idx = bid - 6144;
  const int slab = idx & 63;
  const int e0 = (idx >> 6) * 64;
  const int mat = slab >> 4, hh = slab & 15;
  const float* src; size_t rs; u16* dstw;
  if (mat == 0)      { src = Wq + (size_t)hh * 65536; rs = 64;   dstw = WT  + (size_t)(hh * 64) * 1024; }
  else if (mat == 1) { src = Wk + (size_t)hh * 65536; rs = 64;   dstw = WT  + (size_t)(1024 * 1024) + (size_t)(hh * 64) * 1024; }
  else if (mat == 2) { src = Wv + (size_t)hh * 65536; rs = 64;   dstw = WT  + (size_t)(2 * 1024 * 1024) + (size_t)(hh * 64) * 1024; }
  else               { src = Wo + hh * 64;            rs = 1024; dstw = WOT + (size_t)(hh * 64) * 1024; }
  const int t = threadIdx.x;
#pragma unroll
  for (int i = 0; i < 16; ++i) {
    int id2 = i * 256 + t; int e = id2 >> 6, dd = id2 & 63;
    tile[e][dd] = src[(size_t)(e0 + e) * rs + dd];
  }
  __syncthreads();
#pragma unroll
  for (int i = 0; i < 16; ++i) {
    int id2 = i * 256 + t; int dd = id2 >> 6, e = id2 & 63;
    dstw[(size_t)dd * 1024 + e0 + e] = f2bf(tile[e][dd]);
  }
}

// ---- 2. fused QKV projection GEMM, BK=32 shallow-LDS dbuf ----------------
// grid (32, 24) = 768 blocks. dbuf 2 x (A 8K | B 8K) = 32 KB -> 3+ blocks/CU,
// ALL 768 resident in one round (kills R8's 1.5-round tail + adds overlap).
__global__ __launch_bounds__(256) void k_gemm_qkv(
    const u16* __restrict__ AQ, const u16* __restrict__ AK, const u16* __restrict__ AV,
    const u16* __restrict__ WT,
    const float* __restrict__ bq, const float* __restrict__ bk, const float* __restrict__ bv,
    u16* __restrict__ Qo, u16* __restrict__ Ko, u16* __restrict__ Vo) {
  __shared__ __align__(16) u16 sh[2][8192];   // per buf: As[0..4096), Bs[4096..8192)
  const int tid = threadIdx.x;
  const int mat = blockIdx.y >> 3;
  const int nblk = blockIdx.y & 7;
  const u16* A = (mat == 0) ? AQ : (mat == 1) ? AK : AV;
  const u16* B = WT + (size_t)mat * (1024 * 1024) + (size_t)nblk * (128 * 1024);
  const float* bias = (mat == 0) ? bq : (mat == 1) ? bk : bv;
  const int m0 = blockIdx.x * 128;
  const int lane = tid & 63, w = tid >> 6;
  const int quad = lane >> 4, l16 = lane & 15;
  const int wr = (w & 1) * 64, wc = (w >> 1) * 64;
  f32x4 acc[4][4] = {};

  // stage kt=0 into buf 0: 512 A-chunks + 512 B-chunks of 16B, 2+2 per thread
#pragma unroll
  for (int i = 0; i < 2; ++i) {
    int c = i * 256 + tid;
    int r = c >> 2, qq = c & 3, qg = qq ^ ((r >> 1) & 3);
    gld16(A + (size_t)(m0 + r) * 1024 + qg * 8, &sh[0][c * 8]);
    gld16(B + (size_t)r * 1024 + qg * 8, &sh[0][4096 + c * 8]);
  }

  for (int t = 0; t < 32; ++t) {
    __syncthreads();
    if (t + 1 < 32) {
      const int kt = (t + 1) * 32;
      u16* buf = sh[(t + 1) & 1];
#pragma unroll
      for (int i = 0; i < 2; ++i) {
        int c = i * 256 + tid;
        int r = c >> 2, qq = c & 3, qg = qq ^ ((r >> 1) & 3);
        gld16(A + (size_t)(m0 + r) * 1024 + kt + qg * 8, &buf[c * 8]);
        gld16(B + (size_t)r * 1024 + kt + qg * 8, &buf[4096 + c * 8]);
      }
    }
    const u16* As = sh[t & 1];
    const u16* Bs = sh[t & 1] + 4096;
    s16x8 af[4], bfr[4];
#pragma unroll
    for (int i = 0; i < 4; ++i) {
      int mm = wr + i * 16 + l16;
      int ql = quad ^ ((mm >> 1) & 3);
      af[i] = *(const s16x8*)&As[(mm * 4 + ql) * 8];
    }
#pragma unroll
    for (int j = 0; j < 4; ++j) {
      int nn = wc + j * 16 + l16;
      int ql = quad ^ ((nn >> 1) & 3);
      bfr[j] = *(const s16x8*)&Bs[(nn * 4 + ql) * 8];
    }
#pragma unroll
    for (int i = 0; i < 4; ++i)
#pragma unroll
      for (int j = 0; j < 4; ++j)
        acc[i][j] = __builtin_amdgcn_mfma_f32_16x16x32_bf16(af[i], bfr[j], acc[i][j], 0, 0, 0);
  }

  // ---- epilogue: repack through LDS (32 KB = both bufs), 16B stores ----
  __syncthreads();
  u16* ep = (u16*)sh;   // 16384 u16 = 32 KB, exactly 128x128
  const float QSCALE = 0.125f * 1.44269504088896340736f;
  if (mat == 2) {
#pragma unroll
    for (int i = 0; i < 4; ++i)
#pragma unroll
      for (int j = 0; j < 4; ++j) {
        int c = wc + j * 16 + l16;
        float bb = bias[nblk * 128 + c];
#pragma unroll
        for (int r = 0; r < 4; ++r) {
          int m = wr + i * 16 + quad * 4 + r;
          ep[c * 128 + (((m >> 3) ^ (c & 7)) * 8) + (m & 7)] = f2h(acc[i][j][r] + bb);
        }
      }
  } else {
    float qs = (mat == 0) ? QSCALE : 1.0f;
#pragma unroll
    for (int i = 0; i < 4; ++i)
#pragma unroll
      for (int j = 0; j < 4; ++j) {
        int c = wc + j * 16 + l16;
        float bb = bias[nblk * 128 + c];
#pragma unroll
        for (int r = 0; r < 4; ++r) {
          int m = wr + i * 16 + quad * 4 + r;
          ep[m * 128 + (((c >> 3) ^ (m & 7)) * 8) + (c & 7)] = f2bf((acc[i][j][r] + bb) * qs);
        }
      }
  }
  __syncthreads();
  const int b = m0 >> 11, s0l = m0 & 2047;
#pragma unroll
  for (int p = 0; p < 8; ++p) {
    int lin = p * 256 + tid;
    int rowi = lin >> 4, ch = lin & 15;
    uint4 d4 = *(const uint4*)&ep[rowi * 128 + ((ch ^ (rowi & 7)) * 8)];
    if (mat == 2) {
      int c = nblk * 128 + rowi, h = c >> 6, d = c & 63;
      *(uint4*)&Vo[((size_t)((b * 16 + h) * 64 + d)) * 2048 + s0l + ch * 8] = d4;
    } else {
      int s = s0l + rowi;
      int cb = nblk * 128 + ch * 8, h = cb >> 6, d = cb & 63;
      u16* dst = (mat == 0) ? Qo : Ko;
      *(uint4*)&dst[((size_t)((b * 16 + h) * 2048 + s)) * 64 + d] = d4;
    }
  }
}

// ---- 3. attention: dbuf K/V staging + VALU diet (unchanged control) ------
__global__ __launch_bounds__(256) void k_attn(const u16* __restrict__ Q,
                                              const u16* __restrict__ K,
                                              const u16* __restrict__ Vt,
                                              u16* __restrict__ Ctx) {
  __shared__ __align__(16) u16 sh[2][128 * 128];   // 2 x (Ks 16K | Vs 16K) = 64 KB
  const int tid = threadIdx.x;
  const int bh = blockIdx.x;
  const int q0 = blockIdx.y * 128;
  const int lane = tid & 63, w = tid >> 6;
  const int quad = lane >> 4, l16 = lane & 15;
  const u16* Qb = Q  + (size_t)bh * (2048 * 64);
  const u16* Kb = K  + (size_t)bh * (2048 * 64);
  const u16* Vb = Vt + (size_t)bh * (64 * 2048);

  s16x8 qf[2][2];
#pragma unroll
  for (int qs = 0; qs < 2; ++qs)
#pragma unroll
    for (int ks = 0; ks < 2; ++ks)
      qf[qs][ks] = *(const s16x8*)(Qb + (size_t)(q0 + w * 32 + qs * 16 + l16) * 64 + ks * 32 + quad * 8);

  h16x8 vones;
#pragma unroll
  for (int i = 0; i < 8; ++i) vones[i] = (_Float16)1.0f;

  f32x4 oacc[4][2] = {};
  f32x4 lacc[2] = {};

#pragma unroll
  for (int i = 0; i < 8; ++i) {
    int c = i * 256 + tid;
    if (c < 1024) {
      int rr = c >> 3, qq = c & 7, qg = qq ^ (rr & 7);
      int pr = (rr & 64) + 32 * ((rr >> 5) & 1) + 8 * ((rr >> 2) & 3) + 4 * ((rr >> 4) & 1) + (rr & 3);
      gld16(Kb + (size_t)pr * 64 + qg * 8, &sh[0][c * 8]);
    } else {
      int cc = c - 1024;
      int rr = cc >> 4, qq = cc & 15, qg = qq ^ (rr & 7);
      gld16(Vb + (size_t)rr * 2048 + qg * 8, &sh[0][8192 + cc * 8]);
    }
  }

  for (int t = 0; t < 16; ++t) {
    __syncthreads();
    if (t + 1 < 16) {
      const int kt = (t + 1) * 128;
      u16* buf = sh[(t + 1) & 1];
#pragma unroll
      for (int i = 0; i < 8; ++i) {
        int c = i * 256 + tid;
        if (c < 1024) {
          int rr = c >> 3, qq = c & 7, qg = qq ^ (rr & 7);
          int pr = (rr & 64) + 32 * ((rr >> 5) & 1) + 8 * ((rr >> 2) & 3) + 4 * ((rr >> 4) & 1) + (rr & 3);
          gld16(Kb + (size_t)(kt + pr) * 64 + qg * 8, &buf[c * 8]);
        } else {
          int cc = c - 1024;
          int rr = cc >> 4, qq = cc & 15, qg = qq ^ (rr & 7);
          gld16(Vb + (size_t)rr * 2048 + kt + qg * 8, &buf[8192 + cc * 8]);
        }
      }
    }
    const u16* Ks = sh[t & 1];
    const u16* Vs = sh[t & 1] + 8192;

    f32x4 sacc[8][2] = {};
#pragma unroll
    for (int ks = 0; ks < 2; ++ks)
#pragma unroll
      for (int mb = 0; mb < 8; ++mb) {
        int row = mb * 16 + l16;
        int slot = (ks * 4 + quad) ^ (l16 & 7);
        s16x8 kf = *(const s16x8*)&Ks[row * 64 + slot * 8];
#pragma unroll
        for (int qs = 0; qs < 2; ++qs)
          sacc[mb][qs] = __builtin_amdgcn_mfma_f32_16x16x32_bf16(kf, qf[qs][ks], sacc[mb][qs], 0, 0, 0);
      }

    h16x8 pb[2][4];
#pragma unroll
    for (int qs = 0; qs < 2; ++qs)
#pragma unroll
      for (int ks2 = 0; ks2 < 4; ++ks2) {
        f32x4 s0 = sacc[2 * ks2][qs], s1 = sacc[2 * ks2 + 1][qs];
        union { h16x8 v; fp16x2 h[4]; } u;
        u.h[0] = __builtin_amdgcn_cvt_pkrtz(__builtin_amdgcn_exp2f(s0[0]),
                                            __builtin_amdgcn_exp2f(s0[1]));
        u.h[1] = __builtin_amdgcn_cvt_pkrtz(__builtin_amdgcn_exp2f(s0[2]),
                                            __builtin_amdgcn_exp2f(s0[3]));
        u.h[2] = __builtin_amdgcn_cvt_pkrtz(__builtin_amdgcn_exp2f(s1[0]),
                                            __builtin_amdgcn_exp2f(s1[1]));
        u.h[3] = __builtin_amdgcn_cvt_pkrtz(__builtin_amdgcn_exp2f(s1[2]),
                                            __builtin_amdgcn_exp2f(s1[3]));
        pb[qs][ks2] = u.v;
      }

#pragma unroll
    for (int ks2 = 0; ks2 < 4; ++ks2)
#pragma unroll
      for (int qs = 0; qs < 2; ++qs)
        lacc[qs] = __builtin_amdgcn_mfma_f32_16x16x32_f16(vones, pb[qs][ks2], lacc[qs], 0, 0, 0);

#pragma unroll
    for (int mbv = 0; mbv < 4; ++mbv) {
      int row = mbv * 16 + l16;
#pragma unroll
      for (int ks2 = 0; ks2 < 4; ++ks2) {
        int slot = (ks2 * 4 + quad) ^ (row & 7);
        h16x8 vf = *(const h16x8*)&Vs[row * 128 + slot * 8];
#pragma unroll
        for (int qs = 0; qs < 2; ++qs)
          oacc[mbv][qs] = __builtin_amdgcn_mfma_f32_16x16x32_f16(vf, pb[qs][ks2], oacc[mbv][qs], 0, 0, 0);
      }
    }
  }

  u16* Os = sh[0];
  __syncthreads();
#pragma unroll
  for (int qs = 0; qs < 2; ++qs) {
    float inv = 1.0f / lacc[qs][0];
#pragma unroll
    for (int mbv = 0; mbv < 4; ++mbv) {
      u16x4 ow;
#pragma unroll
      for (int r = 0; r < 4; ++r) ow[r] = f2bf(oacc[mbv][qs][r] * inv);
      *(u16x4*)&Os[(w * 32 + qs * 16 + l16) * 72 + mbv * 16 + quad * 4] = ow;
    }
  }
  __syncthreads();
  const int b = bh >> 4, h = bh & 15;
#pragma unroll
  for (int p = 0; p < 4; ++p) {
    int lin = p * 256 + tid;
    int rowi = lin >> 3, ch = lin & 7;
    uint4 d4 = *(const uint4*)&Os[rowi * 72 + ch * 8];
    int s = q0 + rowi;
    *(uint4*)&Ctx[(size_t)(b * 2048 + s) * 1024 + h * 64 + ch * 8] = d4;
  }
}

// ---- 4. output projection GEMM, double-buffered (unchanged control) ------
__global__ __launch_bounds__(256) void k_gemm_out(const u16* __restrict__ Actx,
                                                  const u16* __restrict__ WOT,
                                                  const float* __restrict__ bo,
                                                  float* __restrict__ Out) {
  __shared__ __align__(16) u16 sh[2][12288];   // per buf: As[0..8192), Bs[8192..12288)
  const int tid = threadIdx.x;
  const int n0 = blockIdx.y * 64;
  const u16* B = WOT + (size_t)n0 * 1024;
  const int m0 = blockIdx.x * 128;
  const int lane = tid & 63, w = tid >> 6;
  const int quad = lane >> 4, l16 = lane & 15;
  f32x4 acc[2][4] = {};

#pragma unroll
  for (int i = 0; i < 4; ++i) {
    int c = i * 256 + tid;
    int r = c >> 3, qq = c & 7, qg = qq ^ (r & 7);
    gld16(Actx + (size_t)(m0 + r) * 1024 + qg * 8, &sh[0][c * 8]);
    if (i < 2)
      gld16(B + (size_t)r * 1024 + qg * 8, &sh[0][8192 + c * 8]);
  }

  for (int t = 0; t < 16; ++t) {
    __syncthreads();
    if (t + 1 < 16) {
      const int kt = (t + 1) * 64;
      u16* buf = sh[(t + 1) & 1];
#pragma unroll
      for (int i = 0; i < 4; ++i) {
        int c = i * 256 + tid;
        int r = c >> 3, qq = c & 7, qg = qq ^ (r & 7);
        gld16(Actx + (size_t)(m0 + r) * 1024 + kt + qg * 8, &buf[c * 8]);
        if (i < 2)
          gld16(B + (size_t)r * 1024 + kt + qg * 8, &buf[8192 + c * 8]);
      }
    }
    const u16* As = sh[t & 1];
    const u16* Bs = sh[t & 1] + 8192;
#pragma unroll
    for (int ks = 0; ks < 2; ++ks) {
      s16x8 af[2], bfr[4];
#pragma unroll
      for (int i = 0; i < 2; ++i) {
        int mm = w * 32 + i * 16 + l16;
        int ql = (ks * 4 + quad) ^ (mm & 7);
        af[i] = *(const s16x8*)&As[(mm * 8 + ql) * 8];
      }
#pragma unroll
      for (int j = 0; j < 4; ++j) {
        int nn = j * 16 + l16;
        int ql = (ks * 4 + quad) ^ (nn & 7);
        bfr[j] = *(const s16x8*)&Bs[(nn * 8 + ql) * 8];
      }
#pragma unroll
      for (int i = 0; i < 2; ++i)
#pragma unroll
        for (int j = 0; j < 4; ++j)
          acc[i][j] = __builtin_amdgcn_mfma_f32_16x16x32_bf16(af[i], bfr[j], acc[i][j], 0, 0, 0);
    }
  }

  __syncthreads();
  float* shf = (float*)&sh[0][0];
#pragma unroll
  for (int i = 0; i < 2; ++i)
#pragma unroll
    for (int j = 0; j < 4; ++j) {
      int col = j * 16 + l16;
      float bb = bo[n0 + col];
#pragma unroll
      for (int r = 0; r < 4; ++r) {
        int row = w * 32 + i * 16 + quad * 4 + r;
        shf[row * 68 + col] = acc[i][j][r] + bb;
      }
    }
  __syncthreads();
#pragma unroll
  for (int p = 0; p < 8; ++p) {
    int lin = p * 256 + tid;
    int rowl = lin >> 4, ch = lin & 15;
    float4 d4 = *(const float4*)&shf[rowl * 68 + ch * 4];
    *(float4*)&Out[(size_t)(m0 + rowl) * 1024 + n0 + ch * 4] = d4;
  }
}

// ---- launch ---------------------------------------------------------------

extern "C" void kernel_launch(void* const* d_in, const int* in_sizes, int n_in,
                              void* d_out, int out_size, void* d_ws, size_t ws_size,
                              hipStream_t stream) {
  const float* q  = (const float*)d_in[0];
  const float* k  = (const float*)d_in[1];
  const float* v  = (const float*)d_in[2];
  const float* Wq = (const float*)d_in[3];
  const float* bq = (const float*)d_in[4];
  const float* Wk = (const float*)d_in[5];
  const float* bk = (const float*)d_in[6];
  const float* Wv = (const float*)d_in[7];
  const float* bv = (const float*)d_in[8];
  const float* Wo = (const float*)d_in[9];
  const float* bo = (const float*)d_in[10];
  float* out = (float*)d_out;

  char* ws = (char*)d_ws;
  u16* ABUF = (u16*)(ws + 0);          // 3 x [4096][1024] bf16 (q,k,v) = 24 MB
  u16* WT   = (u16*)(ws + 25165824);   // 3 x [1024][1024] bf16 = 6 MB
  u16* WOT  = (u16*)(ws + 31457280);   // [1024][1024] bf16 = 2 MB
  u16* QB   = (u16*)(ws + 33554432);   // [B,H,S,D] bf16 = 8 MB
  u16* KB   = (u16*)(ws + 41943040);   // [B,H,S,D] bf16 = 8 MB
  u16* VTB  = (u16*)(ws + 50331648);   // [B,H,D,S] f16  = 8 MB
  u16* CTX  = (u16*)(ws + 58720256);   // [4096][1024] bf16 = 8 MB

  hipLaunchKernelGGL(k_prep, dim3(7168), dim3(256), 0, stream,
                     q, k, v, Wq, Wk, Wv, Wo, ABUF, WT, WOT);
  hipLaunchKernelGGL(k_gemm_qkv, dim3(32, 24), dim3(256), 0, stream,
                     ABUF, ABUF + 4194304, ABUF + 8388608, WT, bq, bk, bv, QB, KB, VTB);
  hipLaunchKernelGGL(k_attn, dim3(32, 16), dim3(256), 0, stream, QB, KB, VTB, CTX);
  hipLaunchKernelGGL(k_gemm_out, dim3(32, 16), dim3(256), 0, stream, CTX, WOT, bo, out);
}